// Round 12
// baseline (87.481 us; speedup 1.0000x reference)
//
#include <hip/hip_runtime.h>

// DataTermLayer: per-pixel optical-flow data-term update.
// Inputs (float32, each B*H*W = 16*1024*1024):
//   d_in[0]=I1, d_in[1]=I2, d_in[2]=u, d_in[3]=v
// Output: d_out = [u_next (N floats) | v_next (N floats)]
//
// Faithful-to-reference: grad_x := dy (vertical diff), grad_y := dx
// (horizontal diff) — the Python source swaps them.
//
// R12 = R8 (best, 65.9us) + three additive micro-levers (R9-R11 proved
// structural rewrites regress; HBM is ~70% duty, the dominant pipe):
//  1. ds_read2_b32 gather pairs: S[q],S[q+1] as one 8B LDS read via an
//     aligned(4) f32x2 -> 16 -> 8 gather instructions per thread.
//  2. vertical halo 3 up / 4 down (|0.5*flow|max ~2.75 < 3; global
//     fallback still guards): LH 17->15, fill 10->9 iters. Horizontal
//     halo stays 4 so gradient ds_read_b128 rows remain 16B-aligned.
//  3. nontemporal loads for u/v/I2 (single-use streams) to preserve
//     L2/L3 residency of I1 halo lines.

#define ALPHA 0.15f
#define IMG_H 1024
#define IMG_W 1024
#define TW 128
#define TH 8
#define HTOP 3
#define HLEFT 4
#define LW 140          // 4 left halo + 128 + 8 right; rows 16B-aligned
#define LH 15           // 3 top halo + 8 + 4 bottom
#define LDS_N (LH * LW) // 2100

typedef float f32x4 __attribute__((ext_vector_type(4)));
typedef float f32x2a4 __attribute__((ext_vector_type(2), aligned(4)));

__global__ __launch_bounds__(256) void dataterm_kernel(
        const float* __restrict__ I1,
        const float* __restrict__ I2,
        const float* __restrict__ u,
        const float* __restrict__ v,
        float* __restrict__ out_u,
        float* __restrict__ out_v) {
    const int W = IMG_W, H = IMG_H;
    const int t   = threadIdx.x;
    const int tx0 = blockIdx.x * TW;
    const int ty0 = blockIdx.y * TH;
    const int b   = blockIdx.z;

    const float* __restrict__ I1b = I1 + (size_t)b * (size_t)(H * W);

    __shared__ float S[LDS_N];

    // thread -> 4 consecutive pixels of one row
    const int r  = t >> 5;           // row within tile, 0..7
    const int cb = (t & 31) << 2;    // col base within tile, 0..124
    const int h  = ty0 + r;
    const int wb = tx0 + cb;
    const int p  = (b * H + h) * W + wb;

    // --- register loads first (nontemporal: single-use streams) ---
    f32x4 u4  = __builtin_nontemporal_load((const f32x4*)(u + p));
    f32x4 v4  = __builtin_nontemporal_load((const f32x4*)(v + p));
    f32x4 i24 = __builtin_nontemporal_load((const f32x4*)(I2 + p));

    // --- cooperative clamped tile fill (scalar; vec fill regressed 2x) ---
    #pragma unroll
    for (int j = 0; j < 9; ++j) {
        int f = t + 256 * j;                     // 0..2303
        if (f < LDS_N) {
            int ly = f / LW;
            int lx = f - ly * LW;
            int gy = min(max(ty0 - HTOP + ly, 0), H - 1);
            int gx = min(max(tx0 - HLEFT + lx, 0), W - 1);
            S[f] = I1b[gy * W + gx];
        }
    }
    __syncthreads();

    // --- gradients from LDS via conflict-free ds_read_b128 ---
    const int cl = (HTOP + r) * LW + HLEFT + cb;  // 16B-aligned
    f32x4 c4 = *(const f32x4*)(S + cl);
    f32x4 d4 = *(const f32x4*)(S + cl + LW);
    float c4r = S[cl + 4];

    float gyv[4] = { d4.x - c4.x, d4.y - c4.y, d4.z - c4.z, d4.w - c4.w };
    float gxv[4] = { c4.y - c4.x, c4.z - c4.y, c4.w - c4.z, c4r - c4.w };

    float uu[4] = { u4.x, u4.y, u4.z, u4.w };
    float vv[4] = { v4.x, v4.y, v4.z, v4.w };
    float i2[4] = { i24.x, i24.y, i24.z, i24.w };
    float ru[4], rv[4];

    #pragma unroll
    for (int i = 0; i < 4; ++i) {
        float x = (float)(wb + i) + 0.5f * uu[i];
        float y = (float)h        + 0.5f * vv[i];

        float x0f = floorf(x);
        float y0f = floorf(y);
        float wx1 = x - x0f;
        float wx0 = 1.0f - wx1;
        float wy1 = y - y0f;
        float wy0 = 1.0f - wy1;

        int x0 = (int)x0f, y0 = (int)y0f;
        int x1 = x0 + 1,   y1 = y0 + 1;

        float vx0 = (x0 >= 0 && x0 <= W - 1) ? 1.0f : 0.0f;
        float vx1 = (x1 >= 0 && x1 <= W - 1) ? 1.0f : 0.0f;
        float vy0 = (y0 >= 0 && y0 <= H - 1) ? 1.0f : 0.0f;
        float vy1 = (y1 >= 0 && y1 <= H - 1) ? 1.0f : 0.0f;

        int lx0 = x0 - tx0 + HLEFT;
        int ly0 = y0 - ty0 + HTOP;

        float g00, g01, g10, g11;
        if ((unsigned)lx0 <= (unsigned)(LW - 2) &&
            (unsigned)ly0 <= (unsigned)(LH - 2)) {
            // in-tile (the always case): paired 8B LDS reads (ds_read2_b32)
            int q = ly0 * LW + lx0;
            f32x2a4 q0 = *(const f32x2a4*)(S + q);
            f32x2a4 q1 = *(const f32x2a4*)(S + q + LW);
            g00 = q0.x * (vy0 * vx0);
            g01 = q0.y * (vy0 * vx1);
            g10 = q1.x * (vy1 * vx0);
            g11 = q1.y * (vy1 * vx1);
        } else {
            // out-of-halo fallback (never taken for 0.5*N(0,1) flow)
            int x0c = min(max(x0, 0), W - 1);
            int x1c = min(max(x1, 0), W - 1);
            int y0c = min(max(y0, 0), H - 1);
            int y1c = min(max(y1, 0), H - 1);
            g00 = I1b[y0c * W + x0c] * (vy0 * vx0);
            g01 = I1b[y0c * W + x1c] * (vy0 * vx1);
            g10 = I1b[y1c * W + x0c] * (vy1 * vx0);
            g11 = I1b[y1c * W + x1c] * (vy1 * vx1);
        }

        float warped = g00 * (wy0 * wx0)
                     + g01 * (wy0 * wx1)
                     + g10 * (wy1 * wx0)
                     + g11 * (wy1 * wx1);

        float dataTerm = warped - i2[i];
        ru[i] = uu[i] - ALPHA * dataTerm * gyv[i];
        rv[i] = vv[i] - ALPHA * dataTerm * gxv[i];
    }

    f32x4 ruv = { ru[0], ru[1], ru[2], ru[3] };
    f32x4 rvv = { rv[0], rv[1], rv[2], rv[3] };
    __builtin_nontemporal_store(ruv, (f32x4*)(out_u + p));
    __builtin_nontemporal_store(rvv, (f32x4*)(out_v + p));
}

extern "C" void kernel_launch(void* const* d_in, const int* in_sizes, int n_in,
                              void* d_out, int out_size, void* d_ws, size_t ws_size,
                              hipStream_t stream) {
    const float* I1 = (const float*)d_in[0];
    const float* I2 = (const float*)d_in[1];
    const float* u  = (const float*)d_in[2];
    const float* v  = (const float*)d_in[3];

    int total = in_sizes[0];               // B*H*W = 16 * 1024 * 1024
    float* out_u = (float*)d_out;
    float* out_v = (float*)d_out + total;

    dim3 grid(IMG_W / TW, IMG_H / TH, total / (IMG_H * IMG_W));
    dataterm_kernel<<<grid, dim3(256), 0, stream>>>(I1, I2, u, v, out_u, out_v);
}

// Round 13
// 84.600 us; speedup vs baseline: 1.0341x; 1.0341x over previous
//
#include <hip/hip_runtime.h>

// DataTermLayer: per-pixel optical-flow data-term update.
// Inputs (float32, each B*H*W = 16*1024*1024):
//   d_in[0]=I1, d_in[1]=I2, d_in[2]=u, d_in[3]=v
// Output: d_out = [u_next (N floats) | v_next (N floats)]
//
// Faithful-to-reference: grad_x := dy (vertical diff), grad_y := dx
// (horizontal diff) — the Python source swaps them.
//
// R13 = R12 minus the nontemporal u/v/I2 loads (identified as the bench
// regression: NT loads killed cross-replay L3 retention of the 201MB
// u/v/I2 streams — invisible in rocprof whose spaced dispatches evict L3
// anyway, but -22us in the back-to-back bench regime). Keeps R12's LDS
// levers, which improved rocprof-isolated time 123->90us:
//  1. ds_read2_b32 gather pairs (aligned(4) f32x2): 16->8 gather ops.
//  2. vertical halo 3 up / 4 down: LH 17->15, fill 10->9 iters.
// NT *stores* remain (outputs never re-read; present since R3 incl. R8).

#define ALPHA 0.15f
#define IMG_H 1024
#define IMG_W 1024
#define TW 128
#define TH 8
#define HTOP 3
#define HLEFT 4
#define LW 140          // 4 left halo + 128 + 8 right; rows 16B-aligned
#define LH 15           // 3 top halo + 8 + 4 bottom
#define LDS_N (LH * LW) // 2100

typedef float f32x4 __attribute__((ext_vector_type(4)));
typedef float f32x2a4 __attribute__((ext_vector_type(2), aligned(4)));

__global__ __launch_bounds__(256) void dataterm_kernel(
        const float* __restrict__ I1,
        const float* __restrict__ I2,
        const float* __restrict__ u,
        const float* __restrict__ v,
        float* __restrict__ out_u,
        float* __restrict__ out_v) {
    const int W = IMG_W, H = IMG_H;
    const int t   = threadIdx.x;
    const int tx0 = blockIdx.x * TW;
    const int ty0 = blockIdx.y * TH;
    const int b   = blockIdx.z;

    const float* __restrict__ I1b = I1 + (size_t)b * (size_t)(H * W);

    __shared__ float S[LDS_N];

    // thread -> 4 consecutive pixels of one row
    const int r  = t >> 5;           // row within tile, 0..7
    const int cb = (t & 31) << 2;    // col base within tile, 0..124
    const int h  = ty0 + r;
    const int wb = tx0 + cb;
    const int p  = (b * H + h) * W + wb;

    // --- register loads first: HBM latency overlaps the fill ---
    f32x4 u4  = *(const f32x4*)(u + p);
    f32x4 v4  = *(const f32x4*)(v + p);
    f32x4 i24 = *(const f32x4*)(I2 + p);

    // --- cooperative clamped tile fill (scalar) ---
    #pragma unroll
    for (int j = 0; j < 9; ++j) {
        int f = t + 256 * j;                     // 0..2303
        if (f < LDS_N) {
            int ly = f / LW;
            int lx = f - ly * LW;
            int gy = min(max(ty0 - HTOP + ly, 0), H - 1);
            int gx = min(max(tx0 - HLEFT + lx, 0), W - 1);
            S[f] = I1b[gy * W + gx];
        }
    }
    __syncthreads();

    // --- gradients from LDS via conflict-free ds_read_b128 ---
    const int cl = (HTOP + r) * LW + HLEFT + cb;  // 16B-aligned
    f32x4 c4 = *(const f32x4*)(S + cl);
    f32x4 d4 = *(const f32x4*)(S + cl + LW);
    float c4r = S[cl + 4];

    float gyv[4] = { d4.x - c4.x, d4.y - c4.y, d4.z - c4.z, d4.w - c4.w };
    float gxv[4] = { c4.y - c4.x, c4.z - c4.y, c4.w - c4.z, c4r - c4.w };

    float uu[4] = { u4.x, u4.y, u4.z, u4.w };
    float vv[4] = { v4.x, v4.y, v4.z, v4.w };
    float i2[4] = { i24.x, i24.y, i24.z, i24.w };
    float ru[4], rv[4];

    #pragma unroll
    for (int i = 0; i < 4; ++i) {
        float x = (float)(wb + i) + 0.5f * uu[i];
        float y = (float)h        + 0.5f * vv[i];

        float x0f = floorf(x);
        float y0f = floorf(y);
        float wx1 = x - x0f;
        float wx0 = 1.0f - wx1;
        float wy1 = y - y0f;
        float wy0 = 1.0f - wy1;

        int x0 = (int)x0f, y0 = (int)y0f;
        int x1 = x0 + 1,   y1 = y0 + 1;

        float vx0 = (x0 >= 0 && x0 <= W - 1) ? 1.0f : 0.0f;
        float vx1 = (x1 >= 0 && x1 <= W - 1) ? 1.0f : 0.0f;
        float vy0 = (y0 >= 0 && y0 <= H - 1) ? 1.0f : 0.0f;
        float vy1 = (y1 >= 0 && y1 <= H - 1) ? 1.0f : 0.0f;

        int lx0 = x0 - tx0 + HLEFT;
        int ly0 = y0 - ty0 + HTOP;

        float g00, g01, g10, g11;
        if ((unsigned)lx0 <= (unsigned)(LW - 2) &&
            (unsigned)ly0 <= (unsigned)(LH - 2)) {
            // in-tile (the always case): paired 8B LDS reads (ds_read2_b32)
            int q = ly0 * LW + lx0;
            f32x2a4 q0 = *(const f32x2a4*)(S + q);
            f32x2a4 q1 = *(const f32x2a4*)(S + q + LW);
            g00 = q0.x * (vy0 * vx0);
            g01 = q0.y * (vy0 * vx1);
            g10 = q1.x * (vy1 * vx0);
            g11 = q1.y * (vy1 * vx1);
        } else {
            // out-of-halo fallback (never taken for 0.5*N(0,1) flow)
            int x0c = min(max(x0, 0), W - 1);
            int x1c = min(max(x1, 0), W - 1);
            int y0c = min(max(y0, 0), H - 1);
            int y1c = min(max(y1, 0), H - 1);
            g00 = I1b[y0c * W + x0c] * (vy0 * vx0);
            g01 = I1b[y0c * W + x1c] * (vy0 * vx1);
            g10 = I1b[y1c * W + x0c] * (vy1 * vx0);
            g11 = I1b[y1c * W + x1c] * (vy1 * vx1);
        }

        float warped = g00 * (wy0 * wx0)
                     + g01 * (wy0 * wx1)
                     + g10 * (wy1 * wx0)
                     + g11 * (wy1 * wx1);

        float dataTerm = warped - i2[i];
        ru[i] = uu[i] - ALPHA * dataTerm * gyv[i];
        rv[i] = vv[i] - ALPHA * dataTerm * gxv[i];
    }

    f32x4 ruv = { ru[0], ru[1], ru[2], ru[3] };
    f32x4 rvv = { rv[0], rv[1], rv[2], rv[3] };
    __builtin_nontemporal_store(ruv, (f32x4*)(out_u + p));
    __builtin_nontemporal_store(rvv, (f32x4*)(out_v + p));
}

extern "C" void kernel_launch(void* const* d_in, const int* in_sizes, int n_in,
                              void* d_out, int out_size, void* d_ws, size_t ws_size,
                              hipStream_t stream) {
    const float* I1 = (const float*)d_in[0];
    const float* I2 = (const float*)d_in[1];
    const float* u  = (const float*)d_in[2];
    const float* v  = (const float*)d_in[3];

    int total = in_sizes[0];               // B*H*W = 16 * 1024 * 1024
    float* out_u = (float*)d_out;
    float* out_v = (float*)d_out + total;

    dim3 grid(IMG_W / TW, IMG_H / TH, total / (IMG_H * IMG_W));
    dataterm_kernel<<<grid, dim3(256), 0, stream>>>(I1, I2, u, v, out_u, out_v);
}

// Round 14
// 65.673 us; speedup vs baseline: 1.3321x; 1.2882x over previous
//
#include <hip/hip_runtime.h>

// DataTermLayer: per-pixel optical-flow data-term update.
// Inputs (float32, each B*H*W = 16*1024*1024):
//   d_in[0]=I1, d_in[1]=I2, d_in[2]=u, d_in[3]=v
// Output: d_out = [u_next (N floats) | v_next (N floats)]
//
// Faithful-to-reference: grad_x := dy (vertical diff), grad_y := dx
// (horizontal diff) — the Python source swaps them.
//
// R14 = byte-exact revert to R8, the measured optimum (65.9us bench).
// Post-R8 history: R9 (bigger tile/vec fill) 75.5, R10 (vec fill) 71.9,
// R11 (persistent ring) 70.5, R12 (LDS levers + NT loads) 87.5, R13
// (LDS levers) 84.6 — five improvement axes, all regressions. R8's
// balance of occupancy, barrier scope, warm-L3 behavior, and gather
// overlap is the practical optimum for this op: ~67% of achievable HBM
// BW (276MB HBM traffic @ ~4.2 TB/s effective), remaining gap is
// divergent bilinear-gather latency no tested structure hides better.
//
// Structure: 128x8 tile +4/+5 halo in LDS (10KB), 256 thr, 4 px/thread.
// u/v/I2 hoisted above the fill; clamped scalar fill (edge-zero
// gradients automatic); gradients via conflict-free ds_read_b128
// (LW=140 keeps rows 16B-aligned); bilinear gathers scalar/unswizzled
// (statistical conflicts proven overlapped, R6); nontemporal f32x4
// output stores; out-of-halo global fallback for arbitrary inputs.

#define ALPHA 0.15f
#define IMG_H 1024
#define IMG_W 1024
#define TW 128
#define TH 8
#define HALO 4
#define LW 140          // 4 left halo + 128 + 8 right; rows 16B-aligned
#define LH 17           // 4 top halo + 8 + 5 bottom
#define LDS_N 2560      // 10 * 256 >= LH*LW (=2380)

typedef float f32x4 __attribute__((ext_vector_type(4)));

__global__ __launch_bounds__(256) void dataterm_kernel(
        const float* __restrict__ I1,
        const float* __restrict__ I2,
        const float* __restrict__ u,
        const float* __restrict__ v,
        float* __restrict__ out_u,
        float* __restrict__ out_v) {
    const int W = IMG_W, H = IMG_H;
    const int t   = threadIdx.x;
    const int tx0 = blockIdx.x * TW;
    const int ty0 = blockIdx.y * TH;
    const int b   = blockIdx.z;

    const float* __restrict__ I1b = I1 + (size_t)b * (size_t)(H * W);

    __shared__ float S[LDS_N];

    // thread -> 4 consecutive pixels of one row
    const int r  = t >> 5;           // row within tile, 0..7
    const int cb = (t & 31) << 2;    // col base within tile, 0..124
    const int h  = ty0 + r;
    const int wb = tx0 + cb;
    const int p  = (b * H + h) * W + wb;

    // --- register loads first: HBM latency overlaps the fill ---
    f32x4 u4  = *(const f32x4*)(u + p);
    f32x4 v4  = *(const f32x4*)(v + p);
    f32x4 i24 = *(const f32x4*)(I2 + p);

    // --- cooperative clamped tile fill (branchless, 10 iters) ---
    #pragma unroll
    for (int j = 0; j < 10; ++j) {
        int f  = t + 256 * j;                    // 0..2559
        int ly = f / LW;                         // 0..18
        int lx = f - ly * LW;
        int gy = min(max(ty0 - HALO + min(ly, LH - 1), 0), H - 1);
        int gx = min(max(tx0 - HALO + lx, 0), W - 1);
        S[f] = I1b[gy * W + gx];
    }
    __syncthreads();

    // --- gradients from LDS via conflict-free ds_read_b128 ---
    const int cl = (HALO + r) * LW + HALO + cb;  // 16B-aligned
    f32x4 c4 = *(const f32x4*)(S + cl);
    f32x4 d4 = *(const f32x4*)(S + cl + LW);
    float c4r = S[cl + 4];

    float gyv[4] = { d4.x - c4.x, d4.y - c4.y, d4.z - c4.z, d4.w - c4.w };
    float gxv[4] = { c4.y - c4.x, c4.z - c4.y, c4.w - c4.z, c4r - c4.w };

    float uu[4] = { u4.x, u4.y, u4.z, u4.w };
    float vv[4] = { v4.x, v4.y, v4.z, v4.w };
    float i2[4] = { i24.x, i24.y, i24.z, i24.w };
    float ru[4], rv[4];

    #pragma unroll
    for (int i = 0; i < 4; ++i) {
        float x = (float)(wb + i) + 0.5f * uu[i];
        float y = (float)h        + 0.5f * vv[i];

        float x0f = floorf(x);
        float y0f = floorf(y);
        float wx1 = x - x0f;
        float wx0 = 1.0f - wx1;
        float wy1 = y - y0f;
        float wy0 = 1.0f - wy1;

        int x0 = (int)x0f, y0 = (int)y0f;
        int x1 = x0 + 1,   y1 = y0 + 1;

        float vx0 = (x0 >= 0 && x0 <= W - 1) ? 1.0f : 0.0f;
        float vx1 = (x1 >= 0 && x1 <= W - 1) ? 1.0f : 0.0f;
        float vy0 = (y0 >= 0 && y0 <= H - 1) ? 1.0f : 0.0f;
        float vy1 = (y1 >= 0 && y1 <= H - 1) ? 1.0f : 0.0f;

        int lx0 = x0 - tx0 + HALO;
        int ly0 = y0 - ty0 + HALO;

        float g00, g01, g10, g11;
        if ((unsigned)lx0 <= (unsigned)(LW - 2) &&
            (unsigned)ly0 <= (unsigned)(LH - 2)) {
            // in-tile (the always case): gather from LDS
            int q = ly0 * LW + lx0;
            g00 = S[q]          * (vy0 * vx0);
            g01 = S[q + 1]      * (vy0 * vx1);
            g10 = S[q + LW]     * (vy1 * vx0);
            g11 = S[q + LW + 1] * (vy1 * vx1);
        } else {
            // out-of-halo fallback (never taken for 0.5*N(0,1) flow)
            int x0c = min(max(x0, 0), W - 1);
            int x1c = min(max(x1, 0), W - 1);
            int y0c = min(max(y0, 0), H - 1);
            int y1c = min(max(y1, 0), H - 1);
            g00 = I1b[y0c * W + x0c] * (vy0 * vx0);
            g01 = I1b[y0c * W + x1c] * (vy0 * vx1);
            g10 = I1b[y1c * W + x0c] * (vy1 * vx0);
            g11 = I1b[y1c * W + x1c] * (vy1 * vx1);
        }

        float warped = g00 * (wy0 * wx0)
                     + g01 * (wy0 * wx1)
                     + g10 * (wy1 * wx0)
                     + g11 * (wy1 * wx1);

        float dataTerm = warped - i2[i];
        ru[i] = uu[i] - ALPHA * dataTerm * gyv[i];
        rv[i] = vv[i] - ALPHA * dataTerm * gxv[i];
    }

    f32x4 ruv = { ru[0], ru[1], ru[2], ru[3] };
    f32x4 rvv = { rv[0], rv[1], rv[2], rv[3] };
    __builtin_nontemporal_store(ruv, (f32x4*)(out_u + p));
    __builtin_nontemporal_store(rvv, (f32x4*)(out_v + p));
}

extern "C" void kernel_launch(void* const* d_in, const int* in_sizes, int n_in,
                              void* d_out, int out_size, void* d_ws, size_t ws_size,
                              hipStream_t stream) {
    const float* I1 = (const float*)d_in[0];
    const float* I2 = (const float*)d_in[1];
    const float* u  = (const float*)d_in[2];
    const float* v  = (const float*)d_in[3];

    int total = in_sizes[0];               // B*H*W = 16 * 1024 * 1024
    float* out_u = (float*)d_out;
    float* out_v = (float*)d_out + total;

    dim3 grid(IMG_W / TW, IMG_H / TH, total / (IMG_H * IMG_W));
    dataterm_kernel<<<grid, dim3(256), 0, stream>>>(I1, I2, u, v, out_u, out_v);
}